// Round 9
// baseline (871.491 us; speedup 1.0000x reference)
//
#include <hip/hip_runtime.h>
#include <hip/hip_bf16.h>

// Problem constants: B=128, T=512, V=50000, E=100, U=128, K=32
#define B_  128
#define T_  512
#define E_  100
#define U_  128
#define K_  32
#define G4  512   // 4*U
#define KP  128   // padded K for MFMA GEMM
#define GRP 8     // lstm time-group size

typedef _Float16 h2_t __attribute__((ext_vector_type(2)));
typedef __fp16   h2raw_t __attribute__((ext_vector_type(2)));
typedef short    bf16x8 __attribute__((ext_vector_type(8)));
typedef float    f32x4  __attribute__((ext_vector_type(4)));

__device__ __forceinline__ h2_t pk2(float a, float b) {
    h2raw_t r = __builtin_amdgcn_cvt_pkrtz(a, b);
    union { h2raw_t r; h2_t h; } u; u.r = r; return u.h;
}
__device__ __forceinline__ int h2_as_int(h2_t v) { union { h2_t h; int i; } u; u.h = v; return u.i; }
__device__ __forceinline__ h2_t int_as_h2(int v) { union { h2_t h; int i; } u; u.i = v; return u.h; }
__device__ __forceinline__ float bperm_f(int byte_idx, float v) {
    return __int_as_float(__builtin_amdgcn_ds_bpermute(byte_idx, __float_as_int(v)));
}

#if __has_builtin(__builtin_amdgcn_fdot2)
__device__ __forceinline__ float fdot2_f(h2_t a, h2_t b, float c) {
    return __builtin_amdgcn_fdot2(a, b, c, false);
}
#else
__device__ __forceinline__ float fdot2_f(h2_t a, h2_t b, float c) {
    return c + (float)a.x * (float)b.x + (float)a.y * (float)b.y;
}
#endif

__device__ __forceinline__ unsigned short bf16_bits(float v) {
    __hip_bfloat16 b = __float2bfloat16(v);
    union { __hip_bfloat16 b; unsigned short s; } u; u.b = b; return u.s;
}

// ---------------------------------------------------------------------------
// Kernel A0: pack Bb[n][k] (n-major, K padded to 128, bf16) from Wk_f|Wk_b.
// ---------------------------------------------------------------------------
__global__ __launch_bounds__(128) void pack_b_kernel(
    const float* __restrict__ Wk_f, const float* __restrict__ Wk_b,
    __hip_bfloat16* __restrict__ Bb)
{
    const int n = blockIdx.x;     // 0..1023
    const int k = threadIdx.x;    // 0..127
    float v = 0.f;
    if (k < E_) v = (n < 512) ? Wk_f[k * 512 + n] : Wk_b[k * 512 + (n - 512)];
    Bb[n * KP + k] = __float2bfloat16(v);
}

// ---------------------------------------------------------------------------
// Kernel A: xk via MFMA (R7 version, B-frags amortized over 8 M-tiles).
// ---------------------------------------------------------------------------
__global__ __launch_bounds__(256, 2) void xk_mfma_kernel(
    const int* __restrict__ tokens, const float* __restrict__ emb,
    const __hip_bfloat16* __restrict__ Bb,
    const float* __restrict__ b_f, const float* __restrict__ b_b,
    __hip_bfloat16* __restrict__ xk_f, __hip_bfloat16* __restrict__ xk_b)
{
    const int n0   = blockIdx.y * 256;
    const int tid  = threadIdx.x;
    const int wv   = tid >> 6;
    const int lane = tid & 63;
    const int quad = lane >> 4;
    const int l16  = lane & 15;

    __shared__ unsigned short A_lds[32][136];
    __shared__ float C_lds[32][268];

    bf16x8 bfr[4][4];
    const unsigned short* Bu = (const unsigned short*)Bb;
    #pragma unroll
    for (int nt = 0; nt < 4; ++nt)
        #pragma unroll
        for (int kc = 0; kc < 4; ++kc)
            bfr[nt][kc] = *(const bf16x8*)(Bu +
                (n0 + wv * 64 + nt * 16 + l16) * KP + kc * 32 + quad * 8);

    const float* bias = (n0 < 512) ? b_f : b_b;
    __hip_bfloat16* outp = (n0 < 512) ? xk_f : xk_b;
    const int nbase = n0 & 511;

    for (int mt8 = 0; mt8 < 8; ++mt8) {
        const int r0 = (blockIdx.x * 8 + mt8) * 32;

        __syncthreads();

        for (int idx = tid; idx < 32 * KP; idx += 256) {
            int r = idx >> 7, k = idx & 127;
            float v = 0.f;
            if (k < E_) v = emb[(long long)tokens[r0 + r] * E_ + k];
            A_lds[r][k] = bf16_bits(v);
        }
        __syncthreads();

        f32x4 acc[2][4];
        #pragma unroll
        for (int mt = 0; mt < 2; ++mt)
            #pragma unroll
            for (int nt = 0; nt < 4; ++nt)
                acc[mt][nt] = (f32x4){0.f, 0.f, 0.f, 0.f};

        #pragma unroll
        for (int mt = 0; mt < 2; ++mt) {
            bf16x8 af[4];
            #pragma unroll
            for (int kc = 0; kc < 4; ++kc)
                af[kc] = *(const bf16x8*)&A_lds[mt * 16 + l16][kc * 32 + quad * 8];
            #pragma unroll
            for (int nt = 0; nt < 4; ++nt)
                #pragma unroll
                for (int kc = 0; kc < 4; ++kc)
                    acc[mt][nt] = __builtin_amdgcn_mfma_f32_16x16x32_bf16(
                        af[kc], bfr[nt][kc], acc[mt][nt], 0, 0, 0);
        }

        #pragma unroll
        for (int mt = 0; mt < 2; ++mt)
            #pragma unroll
            for (int nt = 0; nt < 4; ++nt)
                #pragma unroll
                for (int v = 0; v < 4; ++v)
                    C_lds[mt * 16 + quad * 4 + v][wv * 64 + nt * 16 + l16] =
                        acc[mt][nt][v];
        __syncthreads();

        for (int idx = tid; idx < 32 * 128; idx += 256) {
            int r = idx >> 7, c = (idx & 127) * 2;
            float v0 = C_lds[r][c]     + bias[nbase + c];
            float v1 = C_lds[r][c + 1] + bias[nbase + c + 1];
            unsigned int w = ((unsigned int)bf16_bits(v1) << 16) | bf16_bits(v0);
            *(unsigned int*)(outp + (long long)(r0 + r) * G4 + nbase + c) = w;
        }
    }
}

// ---------------------------------------------------------------------------
// Kernel B: LSTM — single-barrier, wave-local recurrence.
// Wave w owns units [16w,16w+16). Phase 1: 8 readlane (own h pairs) + 64 dot2
// over all 512 columns (lane covers q=lane & q=lane+64, 4 gates). Partials to
// swizzled pl (48 KB, double-buffered). ONE barrier. Phase 2: lane (gp,i)
// sums 8 partials of (gate gp, unit 16w+i) + xk (group-prefetched), z gates
// gathered by 3 bpermutes, 10 trans/lane (lanes 16-63 shadow), h pairs
// repacked by 2 bpermutes -> next readlane. h stores clustered per group.
// ---------------------------------------------------------------------------
__device__ __forceinline__ float sigmoid_f(float x) {
    return 1.f / (1.f + __expf(-x));
}
__device__ __forceinline__ float tanh_f(float x) {
    float e = __expf(2.f * x);
    return 1.f - 2.f / (e + 1.f);
}

__global__ __launch_bounds__(512, 1) void lstm_kernel(
    const __hip_bfloat16* __restrict__ xk_f,
    const __hip_bfloat16* __restrict__ xk_b,
    const float* __restrict__ Wr_f, const float* __restrict__ Wr_b,
    __hip_bfloat16* __restrict__ h_buf)
{
    const int bid  = blockIdx.x;
    const int dir  = bid >> 7;
    const int b    = bid & 127;
    const int tid  = threadIdx.x;
    const int wv   = tid >> 6;       // wave 0..7 -> u-slice [16wv, +16)
    const int lane = tid & 63;
    const int gp   = lane >> 4;      // phase-2 gate
    const int i16  = lane & 15;      // phase-2 unit offset

    const float* Wr = dir ? Wr_b : Wr_f;
    const __hip_bfloat16* xk = dir ? xk_b : xk_f;

    // phase-1 weights: columns q0=lane, q1=lane+64; gates 0..3; 8 u-pairs
    h2_t wp[4][2][8];
    #pragma unroll
    for (int g = 0; g < 4; ++g)
        #pragma unroll
        for (int qh = 0; qh < 2; ++qh)
            #pragma unroll
            for (int p = 0; p < 8; ++p)
                wp[g][qh][p] = pk2(
                    Wr[(16 * wv + 2 * p)     * G4 + g * 128 + lane + 64 * qh],
                    Wr[(16 * wv + 2 * p + 1) * G4 + g * 128 + lane + 64 * qh]);

    // partials: [buf][gate][q][12] (8 slots used, swizzled; rows 48B aligned)
    __shared__ __align__(16) float pl[2][4][U_][12];   // 48 KB

    const int q0 = lane, q1 = lane + 64;
    const int sw0 = (wv + q0 + (q0 >> 3)) & 7;   // conflict-free write slots
    const int sw1 = (wv + q1 + (q1 >> 3)) & 7;

    float c   = 0.f;
    int   hpk = 0;       // lane j<8: packed (h[16wv+2j], h[16wv+2j+1])
    float h_st[GRP];
    #pragma unroll
    for (int d = 0; d < GRP; ++d) h_st[d] = 0.f;

    const long long rowbase = (long long)b * T_;
    const int colm = gp * 128 + 16 * wv + i16;   // this lane's phase-2 column
    const __hip_bfloat16* xkc = xk + rowbase * G4 + colm;

    float ep[GRP];
    #pragma unroll
    for (int d = 0; d < GRP; ++d) {
        int t = dir ? (T_ - 1 - d) : d;
        ep[d] = __bfloat162float(xkc[t * G4]);
    }

    for (int g = 0; g < T_ / GRP; ++g) {
        float en[GRP];
        #pragma unroll
        for (int d = 0; d < GRP; ++d) en[d] = 0.f;
        if (g + 1 < T_ / GRP) {
            #pragma unroll
            for (int d = 0; d < GRP; ++d) {
                int s = (g + 1) * GRP + d;
                int t = dir ? (T_ - 1 - s) : s;
                en[d] = __bfloat162float(xkc[t * G4]);
            }
        }

        #pragma unroll
        for (int d = 0; d < GRP; ++d) {
            const int s   = g * GRP + d;
            const int buf = s & 1;

            // ---- phase 1: own-slice partials for 8 columns ----
            float a00 = 0.f, a01 = 0.f, a10 = 0.f, a11 = 0.f;
            float a20 = 0.f, a21 = 0.f, a30 = 0.f, a31 = 0.f;
            #pragma unroll
            for (int p = 0; p < 8; ++p) {
                h2_t hh = int_as_h2(__builtin_amdgcn_readlane(hpk, p));
                a00 = fdot2_f(hh, wp[0][0][p], a00);
                a01 = fdot2_f(hh, wp[0][1][p], a01);
                a10 = fdot2_f(hh, wp[1][0][p], a10);
                a11 = fdot2_f(hh, wp[1][1][p], a11);
                a20 = fdot2_f(hh, wp[2][0][p], a20);
                a21 = fdot2_f(hh, wp[2][1][p], a21);
                a30 = fdot2_f(hh, wp[3][0][p], a30);
                a31 = fdot2_f(hh, wp[3][1][p], a31);
            }
            pl[buf][0][q0][sw0] = a00;  pl[buf][0][q1][sw1] = a01;
            pl[buf][1][q0][sw0] = a10;  pl[buf][1][q1][sw1] = a11;
            pl[buf][2][q0][sw0] = a20;  pl[buf][2][q1][sw1] = a21;
            pl[buf][3][q0][sw0] = a30;  pl[buf][3][q1][sw1] = a31;
            __syncthreads();             // the ONLY barrier per step

            // ---- phase 2: lane (gp, i16) -> z of (gate gp, unit 16wv+i16) --
            const float* row = &pl[buf][gp][16 * wv + i16][0];
            float4 v0 = *(const float4*)row;
            float4 v1 = *(const float4*)(row + 4);
            float z = ((v0.x + v0.y) + (v0.z + v0.w))
                    + ((v1.x + v1.y) + (v1.z + v1.w)) + ep[d];

            float zf = bperm_f(4 * (i16 + 16), z);
            float zg = bperm_f(4 * (i16 + 32), z);
            float zo = bperm_f(4 * (i16 + 48), z);
            // lanes 0-15: own z is zi (gate 0); lanes 16-63 shadow harmlessly
            c = sigmoid_f(zf) * c + sigmoid_f(z) * tanh_f(zg);
            float h = sigmoid_f(zo) * tanh_f(c);
            h_st[d] = h;

            // repack pairs in-wave: lane j <- (h@lane 2j, h@lane 2j+1)
            float hA = bperm_f(4 * (2 * (lane & 7)),     h);
            float hB = bperm_f(4 * (2 * (lane & 7) + 1), h);
            hpk = h2_as_int(pk2(hA, hB));
        }

        // clustered h stores: lanes 0..15 of each wave cover all 128 units
        if (gp == 0) {
            #pragma unroll
            for (int d = 0; d < GRP; ++d) {
                int s = g * GRP + d;
                int t = dir ? (T_ - 1 - s) : s;
                h_buf[(rowbase + t) * 256 + dir * U_ + 16 * wv + i16] =
                    __float2bfloat16(h_st[d]);
            }
        }

        #pragma unroll
        for (int d = 0; d < GRP; ++d) ep[d] = en[d];
    }
}

// ---------------------------------------------------------------------------
// Kernel C: em = h_buf(65536x256 bf16) @ ck(256x32) + cb  -> f32 (65536x32).
// ---------------------------------------------------------------------------
__global__ __launch_bounds__(256) void em_kernel(
    const __hip_bfloat16* __restrict__ h_buf,
    const float* __restrict__ ck, const float* __restrict__ cb,
    float* __restrict__ em)
{
    const int tid  = threadIdx.x;
    const int part = tid >> 5;
    const int k    = tid & 31;

    float ckr[32];
    #pragma unroll
    for (int i = 0; i < 32; ++i)
        ckr[i] = ck[(part * 32 + i) * K_ + k];
    const float cbk = cb[k];

    __shared__ float h_l[8][256];
    __shared__ float part_l[8][8][K_];

    const int r0 = blockIdx.x * 64;

    for (int round = 0; round < 8; ++round) {
        const int rbase = r0 + round * 8;
        #pragma unroll
        for (int j = 0; j < 8; ++j)
            h_l[j][tid] = __bfloat162float(h_buf[(long long)(rbase + j) * 256 + tid]);
        __syncthreads();

        #pragma unroll
        for (int j = 0; j < 8; ++j) {
            float p = 0.f;
            #pragma unroll
            for (int i = 0; i < 32; ++i)
                p = fmaf(h_l[j][part * 32 + i], ckr[i], p);
            part_l[j][part][k] = p;
        }
        __syncthreads();

        {
            int j2 = tid >> 5;
            float e = cbk;
            #pragma unroll
            for (int p = 0; p < 8; ++p) e += part_l[j2][p][k];
            em[(long long)(rbase + j2) * K_ + k] = e;
        }
        __syncthreads();
    }
}

// ---------------------------------------------------------------------------
// Kernel D: CRF logZ. 128 blocks x 1 wave, alpha/exp(trans) in registers.
// ---------------------------------------------------------------------------
#define PF_ 8
__global__ __launch_bounds__(64) void crf_kernel(
    const float* __restrict__ em,
    const float* __restrict__ trans,
    float* __restrict__ out)
{
    const int b    = blockIdx.x;
    const int lane = threadIdx.x;
    const int k    = lane & 31;
    const int half = lane >> 5;

    float etr[16];
    #pragma unroll
    for (int i = 0; i < 16; ++i)
        etr[i] = __expf(trans[(half * 16 + i) * K_ + k]);

    const float* em_b = em + (long long)b * T_ * K_;

    float ep[PF_];
    #pragma unroll
    for (int d = 0; d < PF_; ++d)
        ep[d] = em_b[d * K_ + k];

    float alpha = 0.f;
    for (int tb = 0; tb < T_; tb += PF_) {
        float en[PF_];
        if (tb + PF_ < T_) {
            #pragma unroll
            for (int d = 0; d < PF_; ++d)
                en[d] = em_b[(tb + PF_ + d) * K_ + k];
        } else {
            #pragma unroll
            for (int d = 0; d < PF_; ++d) en[d] = 0.f;
        }

        #pragma unroll
        for (int d = 0; d < PF_; ++d) {
            const int t = tb + d;
            if (t == 0) {
                alpha = ep[d];
            } else {
                float M = __shfl(alpha, 0, 64);
                float p = __expf(alpha - M);
                float acc = 0.f;
                #pragma unroll
                for (int i = 0; i < 16; ++i) {
                    float pv = __shfl(p, half * 16 + i, 64);
                    acc = fmaf(pv, etr[i], acc);
                }
                acc += __shfl_xor(acc, 32, 64);
                alpha = M + __logf(acc) + ep[d];
            }
        }
        #pragma unroll
        for (int d = 0; d < PF_; ++d) ep[d] = en[d];
    }

    float m = alpha;
    #pragma unroll
    for (int d = 1; d < 32; d <<= 1)
        m = fmaxf(m, __shfl_xor(m, d, 64));
    float s = __expf(alpha - m);
    #pragma unroll
    for (int d = 1; d < 32; d <<= 1)
        s += __shfl_xor(s, d, 64);
    if (lane == 0) out[b] = m + __logf(s);
}

// ---------------------------------------------------------------------------
extern "C" void kernel_launch(void* const* d_in, const int* in_sizes, int n_in,
                              void* d_out, int out_size, void* d_ws, size_t ws_size,
                              hipStream_t stream)
{
    const int*   tokens = (const int*)  d_in[0];
    const float* emb    = (const float*)d_in[1];
    const float* Wk_f   = (const float*)d_in[2];
    const float* Wr_f   = (const float*)d_in[3];
    const float* b_f    = (const float*)d_in[4];
    const float* Wk_b   = (const float*)d_in[5];
    const float* Wr_b   = (const float*)d_in[6];
    const float* b_b    = (const float*)d_in[7];
    const float* ck     = (const float*)d_in[8];
    const float* cb     = (const float*)d_in[9];
    const float* trans  = (const float*)d_in[10];
    float* out = (float*)d_out;

    const long long ROWS = (long long)B_ * T_;     // 65536
    __hip_bfloat16* xk_f  = (__hip_bfloat16*)d_ws;
    __hip_bfloat16* xk_b  = xk_f + ROWS * G4;
    __hip_bfloat16* h_buf = xk_b + ROWS * G4;
    __hip_bfloat16* Bb    = h_buf;                 // alias, safe by ordering
    float* em = (float*)d_ws;                      // alias, safe by ordering

    hipLaunchKernelGGL(pack_b_kernel, dim3(1024), dim3(128), 0, stream,
                       Wk_f, Wk_b, Bb);
    hipLaunchKernelGGL(xk_mfma_kernel, dim3((int)(ROWS / 256), 4), dim3(256), 0,
                       stream, tokens, emb, Bb, b_f, b_b, xk_f, xk_b);
    hipLaunchKernelGGL(lstm_kernel, dim3(256), dim3(512), 0, stream,
                       xk_f, xk_b, Wr_f, Wr_b, h_buf);
    hipLaunchKernelGGL(em_kernel, dim3((int)(ROWS / 64)), dim3(256), 0, stream,
                       h_buf, ck, cb, em);
    hipLaunchKernelGGL(crf_kernel, dim3(B_), dim3(64), 0, stream,
                       em, trans, out);
}